// Round 5
// baseline (328.132 us; speedup 1.0000x reference)
//
#include <hip/hip_runtime.h>
#include <hip/hip_bf16.h>

#define N_NODES 50000
#define N_EDGES 800000
#define IN_FT 256
#define OUT_FT 128

typedef __bf16 bf16;
typedef __attribute__((ext_vector_type(8))) __bf16 bf16x8;
typedef __attribute__((ext_vector_type(4))) __bf16 bf16x4;
typedef __attribute__((ext_vector_type(4))) float floatx4;

static __device__ inline unsigned short f2bf_bits(float f) {
    unsigned u = __float_as_uint(f);
    return (unsigned short)((u + 0x7FFFu + ((u >> 16) & 1u)) >> 16);  // RTNE
}

// ---------------- GEMM: seq_fts[n][o] = sum_i seq[n][i] * W[o][i] ----------
// bf16 MFMA (16x16x32), output stored as bf16 (halves downstream gather bytes).
#define WP 264

__global__ __launch_bounds__(256) void k_gemm(const float* __restrict__ seq,
                                              const float* __restrict__ W,
                                              unsigned short* __restrict__ seq_fts) {
    __shared__ bf16 Wlds[128 * WP];
    const int t = threadIdx.x;

    // ---- stage W -> LDS (bf16), 2 threads per row ----
    {
        const int row  = t >> 1;
        const int half = (t & 1) * 128;
        const float* wr = W + (size_t)row * IN_FT + half;
        bf16* dst = Wlds + row * WP + half;
#pragma unroll
        for (int c = 0; c < 32; ++c) {
            float4 v = *(const float4*)(wr + c * 4);
            bf16x4 b;
            b[0] = (bf16)v.x; b[1] = (bf16)v.y; b[2] = (bf16)v.z; b[3] = (bf16)v.w;
            *(bf16x4*)(dst + c * 4) = b;
        }
    }

    const int lane = t & 63;
    const int wave = t >> 6;
    const int quad = lane >> 4;
    const int l16  = lane & 15;

    // ---- A fragments: lane holds A[m=l16][k=quad*8+j], j=0..7 ----
    int arow = blockIdx.x * 64 + wave * 16 + l16;
    if (arow >= N_NODES) arow = 0;            // clamped; stores are guarded
    const float* ap = seq + (size_t)arow * IN_FT + quad * 8;
    bf16x8 afr[8];
#pragma unroll
    for (int s = 0; s < 8; ++s) {
        float4 v0 = *(const float4*)(ap + s * 32);
        float4 v1 = *(const float4*)(ap + s * 32 + 4);
        bf16x8 a;
        a[0] = (bf16)v0.x; a[1] = (bf16)v0.y; a[2] = (bf16)v0.z; a[3] = (bf16)v0.w;
        a[4] = (bf16)v1.x; a[5] = (bf16)v1.y; a[6] = (bf16)v1.z; a[7] = (bf16)v1.w;
        afr[s] = a;
    }
    __syncthreads();

    const int mbase = blockIdx.x * 64 + wave * 16;
#pragma unroll
    for (int tt = 0; tt < 8; ++tt) {
        floatx4 acc = {0.f, 0.f, 0.f, 0.f};
        const bf16* bp = Wlds + (tt * 16 + l16) * WP + quad * 8;
#pragma unroll
        for (int s = 0; s < 8; ++s) {
            bf16x8 bfr = *(const bf16x8*)(bp + s * 32);
            acc = __builtin_amdgcn_mfma_f32_16x16x32_bf16(afr[s], bfr, acc, 0, 0, 0);
        }
#pragma unroll
        for (int r = 0; r < 4; ++r) {
            int m = mbase + quad * 4 + r;   // C/D: row = quad*4+reg, col = l16
            if (m < N_NODES)
                seq_fts[(size_t)m * OUT_FT + tt * 16 + l16] = f2bf_bits(acc[r]);
        }
    }
}

// ---------------- CSR build ----------------
__global__ void k_zero(int* __restrict__ counts, int n) {
    int i = blockIdx.x * blockDim.x + threadIdx.x;
    if (i < n) counts[i] = 0;
}

__global__ void k_hist(const int* __restrict__ dst, int* __restrict__ counts) {
    int e = blockIdx.x * blockDim.x + threadIdx.x;
    if (e < N_EDGES) atomicAdd(&counts[dst[e]], 1);
}

// ---- device-wide exclusive scan over counts[0..N_NODES) in 3 kernels ----
#define SCAN_B 256
#define NBLK ((N_NODES + SCAN_B - 1) / SCAN_B)   // 196

__global__ __launch_bounds__(SCAN_B) void k_psum(const int* __restrict__ counts,
                                                 int* __restrict__ part) {
    int i = blockIdx.x * SCAN_B + threadIdx.x;
    int v = (i < N_NODES) ? counts[i] : 0;
#pragma unroll
    for (int s = 32; s > 0; s >>= 1) v += __shfl_down(v, s, 64);
    __shared__ int w[4];
    if ((threadIdx.x & 63) == 0) w[threadIdx.x >> 6] = v;
    __syncthreads();
    if (threadIdx.x == 0) part[blockIdx.x] = w[0] + w[1] + w[2] + w[3];
}

__global__ __launch_bounds__(SCAN_B) void k_scanp(const int* __restrict__ part,
                                                  int* __restrict__ partoff,
                                                  int* __restrict__ row_ptr) {
    __shared__ int lds[SCAN_B];
    int tid = threadIdx.x;
    int v = (tid < NBLK) ? part[tid] : 0;
    lds[tid] = v;
    __syncthreads();
#pragma unroll
    for (int s = 1; s < SCAN_B; s <<= 1) {
        int t2 = (tid >= s) ? lds[tid - s] : 0;
        __syncthreads();
        lds[tid] += t2;
        __syncthreads();
    }
    if (tid < NBLK) partoff[tid] = lds[tid] - v;   // exclusive
    if (tid == SCAN_B - 1) row_ptr[N_NODES] = lds[SCAN_B - 1];
}

__global__ __launch_bounds__(SCAN_B) void k_wrscan(const int* __restrict__ counts,
                                                   const int* __restrict__ partoff,
                                                   int* __restrict__ row_ptr) {
    __shared__ int lds[SCAN_B];
    int tid = threadIdx.x;
    int i = blockIdx.x * SCAN_B + tid;
    int v = (i < N_NODES) ? counts[i] : 0;
    lds[tid] = v;
    __syncthreads();
#pragma unroll
    for (int s = 1; s < SCAN_B; s <<= 1) {
        int t2 = (tid >= s) ? lds[tid - s] : 0;
        __syncthreads();
        lds[tid] += t2;
        __syncthreads();
    }
    if (i < N_NODES)
        row_ptr[i] = partoff[blockIdx.x] + lds[tid] - v;
}

// ---- block-ownership fill: block b owns nodes [256b, 256b+256). It scans the
// whole dst array (int4, coalesced, L2-resident since all blocks stream it in
// lockstep) and appends matching edges to ITS contiguous CSR region via LDS
// cursors -> writes are XCD-local full lines (kills the 16x write amp of the
// previous global-atomic scatter).
#define OWN 256
#define FB ((N_NODES + OWN - 1) / OWN)   // 196

__global__ __launch_bounds__(1024) void k_fill_own(const int* __restrict__ src,
                                                   const int* __restrict__ dst,
                                                   const float* __restrict__ val,
                                                   const int* __restrict__ row_ptr,
                                                   unsigned* __restrict__ csr_ev) {
    __shared__ int cur[OWN];
    const int n0 = blockIdx.x * OWN;
    const int t  = threadIdx.x;
    if (t < OWN) {
        int n = n0 + t;
        cur[t] = row_ptr[n < N_NODES ? n : N_NODES];
    }
    __syncthreads();
    const int4* dst4 = (const int4*)dst;
    for (int i = t; i < N_EDGES / 4; i += 1024) {
        int4 d4 = dst4[i];
#pragma unroll
        for (int k = 0; k < 4; ++k) {
            int d = (k == 0) ? d4.x : (k == 1) ? d4.y : (k == 2) ? d4.z : d4.w;
            unsigned rel = (unsigned)(d - n0);
            if (rel < OWN) {
                int e   = i * 4 + k;
                int pos = atomicAdd(&cur[rel], 1);
                unsigned w = (unsigned)(unsigned short)src[e]
                           | ((unsigned)f2bf_bits(val[e]) << 16);
                csr_ev[pos] = w;
            }
        }
    }
}

// ---------------- gather + bias + PReLU ----------------
// one wave per node; lane handles features {2*lane, 2*lane+1} -> one dword
// (bf16x2) gathered per edge per lane = 256 B/row, fully coalesced.
#define GW 4
__global__ __launch_bounds__(64 * GW) void k_gather(const unsigned* __restrict__ fts,
                                                    const int* __restrict__ row_ptr,
                                                    const unsigned* __restrict__ csr_ev,
                                                    const float* __restrict__ bias,
                                                    const float* __restrict__ prelu_a,
                                                    float* __restrict__ out) {
    const int wave = threadIdx.x >> 6;
    const int lane = threadIdx.x & 63;
    const int n = blockIdx.x * GW + wave;
    if (n >= N_NODES) return;
    const int s0 = row_ptr[n];
    const int s1 = row_ptr[n + 1];
    float acc0 = 0.f, acc1 = 0.f;
    int j = s0;
    for (; j + 3 < s1; j += 4) {
        unsigned w0 = csr_ev[j],     w1 = csr_ev[j + 1];
        unsigned w2 = csr_ev[j + 2], w3 = csr_ev[j + 3];
        unsigned p0 = fts[(w0 & 0xFFFFu) * 64u + lane];
        unsigned p1 = fts[(w1 & 0xFFFFu) * 64u + lane];
        unsigned p2 = fts[(w2 & 0xFFFFu) * 64u + lane];
        unsigned p3 = fts[(w3 & 0xFFFFu) * 64u + lane];
        float v0 = __uint_as_float(w0 & 0xFFFF0000u);
        float v1 = __uint_as_float(w1 & 0xFFFF0000u);
        float v2 = __uint_as_float(w2 & 0xFFFF0000u);
        float v3 = __uint_as_float(w3 & 0xFFFF0000u);
        acc0 += v0 * __uint_as_float(p0 << 16);
        acc1 += v0 * __uint_as_float(p0 & 0xFFFF0000u);
        acc0 += v1 * __uint_as_float(p1 << 16);
        acc1 += v1 * __uint_as_float(p1 & 0xFFFF0000u);
        acc0 += v2 * __uint_as_float(p2 << 16);
        acc1 += v2 * __uint_as_float(p2 & 0xFFFF0000u);
        acc0 += v3 * __uint_as_float(p3 << 16);
        acc1 += v3 * __uint_as_float(p3 & 0xFFFF0000u);
    }
    for (; j < s1; ++j) {
        unsigned w0 = csr_ev[j];
        unsigned p0 = fts[(w0 & 0xFFFFu) * 64u + lane];
        float v0 = __uint_as_float(w0 & 0xFFFF0000u);
        acc0 += v0 * __uint_as_float(p0 << 16);
        acc1 += v0 * __uint_as_float(p0 & 0xFFFF0000u);
    }
    float2 b = *(const float2*)&bias[lane * 2];
    float a = prelu_a[0];
    float x0 = acc0 + b.x;
    float x1 = acc1 + b.y;
    x0 = (x0 >= 0.f) ? x0 : a * x0;
    x1 = (x1 >= 0.f) ? x1 : a * x1;
    *(float2*)&out[(size_t)n * OUT_FT + lane * 2] = make_float2(x0, x1);
}

extern "C" void kernel_launch(void* const* d_in, const int* in_sizes, int n_in,
                              void* d_out, int out_size, void* d_ws, size_t ws_size,
                              hipStream_t stream) {
    const float* seq      = (const float*)d_in[0];
    const int*   edge_src = (const int*)d_in[1];
    const int*   edge_dst = (const int*)d_in[2];
    const float* edge_val = (const float*)d_in[3];
    const float* W        = (const float*)d_in[4];
    const float* bias     = (const float*)d_in[5];
    const float* prelu_a  = (const float*)d_in[6];
    float* out = (float*)d_out;

    char* ws = (char*)d_ws;
    size_t off = 0;
    auto alloc = [&](size_t bytes) {
        void* p = ws + off;
        off = (off + bytes + 255) & ~(size_t)255;
        return p;
    };
    unsigned short* seq_fts = (unsigned short*)alloc((size_t)N_NODES * OUT_FT * sizeof(unsigned short));
    int*   row_ptr = (int*)alloc((size_t)(N_NODES + 1) * sizeof(int));
    int*   counts  = (int*)alloc((size_t)N_NODES * sizeof(int));
    int*   part    = (int*)alloc((size_t)NBLK * sizeof(int));
    int*   partoff = (int*)alloc((size_t)NBLK * sizeof(int));
    unsigned* csr_ev = (unsigned*)alloc((size_t)N_EDGES * sizeof(unsigned));
    (void)ws_size; (void)in_sizes; (void)n_in; (void)out_size;

    k_gemm<<<(N_NODES + 63) / 64, 256, 0, stream>>>(seq, W, seq_fts);
    k_zero<<<(N_NODES + 255) / 256, 256, 0, stream>>>(counts, N_NODES);
    k_hist<<<(N_EDGES + 255) / 256, 256, 0, stream>>>(edge_dst, counts);
    k_psum<<<NBLK, SCAN_B, 0, stream>>>(counts, part);
    k_scanp<<<1, SCAN_B, 0, stream>>>(part, partoff, row_ptr);
    k_wrscan<<<NBLK, SCAN_B, 0, stream>>>(counts, partoff, row_ptr);
    k_fill_own<<<FB, 1024, 0, stream>>>(edge_src, edge_dst, edge_val,
                                        row_ptr, csr_ev);
    k_gather<<<(N_NODES + GW - 1) / GW, 64 * GW, 0, stream>>>((const unsigned*)seq_fts,
                                                              row_ptr, csr_ev,
                                                              bias, prelu_a, out);
}

// Round 6
// 198.388 us; speedup vs baseline: 1.6540x; 1.6540x over previous
//
#include <hip/hip_runtime.h>
#include <hip/hip_bf16.h>

#define N_NODES 50000
#define N_EDGES 800000
#define IN_FT 256
#define OUT_FT 128

typedef __bf16 bf16;
typedef __attribute__((ext_vector_type(8))) __bf16 bf16x8;
typedef __attribute__((ext_vector_type(4))) __bf16 bf16x4;
typedef __attribute__((ext_vector_type(4))) float floatx4;

static __device__ inline unsigned short f2bf_bits(float f) {
    unsigned u = __float_as_uint(f);
    return (unsigned short)((u + 0x7FFFu + ((u >> 16) & 1u)) >> 16);  // RTNE
}

// ---------------- GEMM: seq_fts[n][o] = sum_i seq[n][i] * W[o][i] ----------
// bf16 MFMA (16x16x32), output stored as bf16 (halves downstream gather bytes).
#define WP 264

__global__ __launch_bounds__(256) void k_gemm(const float* __restrict__ seq,
                                              const float* __restrict__ W,
                                              unsigned short* __restrict__ seq_fts) {
    __shared__ bf16 Wlds[128 * WP];
    const int t = threadIdx.x;

    // ---- stage W -> LDS (bf16), 2 threads per row ----
    {
        const int row  = t >> 1;
        const int half = (t & 1) * 128;
        const float* wr = W + (size_t)row * IN_FT + half;
        bf16* dst = Wlds + row * WP + half;
#pragma unroll
        for (int c = 0; c < 32; ++c) {
            float4 v = *(const float4*)(wr + c * 4);
            bf16x4 b;
            b[0] = (bf16)v.x; b[1] = (bf16)v.y; b[2] = (bf16)v.z; b[3] = (bf16)v.w;
            *(bf16x4*)(dst + c * 4) = b;
        }
    }

    const int lane = t & 63;
    const int wave = t >> 6;
    const int quad = lane >> 4;
    const int l16  = lane & 15;

    // ---- A fragments: lane holds A[m=l16][k=quad*8+j], j=0..7 ----
    int arow = blockIdx.x * 64 + wave * 16 + l16;
    if (arow >= N_NODES) arow = 0;            // clamped; stores are guarded
    const float* ap = seq + (size_t)arow * IN_FT + quad * 8;
    bf16x8 afr[8];
#pragma unroll
    for (int s = 0; s < 8; ++s) {
        float4 v0 = *(const float4*)(ap + s * 32);
        float4 v1 = *(const float4*)(ap + s * 32 + 4);
        bf16x8 a;
        a[0] = (bf16)v0.x; a[1] = (bf16)v0.y; a[2] = (bf16)v0.z; a[3] = (bf16)v0.w;
        a[4] = (bf16)v1.x; a[5] = (bf16)v1.y; a[6] = (bf16)v1.z; a[7] = (bf16)v1.w;
        afr[s] = a;
    }
    __syncthreads();

    const int mbase = blockIdx.x * 64 + wave * 16;
#pragma unroll
    for (int tt = 0; tt < 8; ++tt) {
        floatx4 acc = {0.f, 0.f, 0.f, 0.f};
        const bf16* bp = Wlds + (tt * 16 + l16) * WP + quad * 8;
#pragma unroll
        for (int s = 0; s < 8; ++s) {
            bf16x8 bfr = *(const bf16x8*)(bp + s * 32);
            acc = __builtin_amdgcn_mfma_f32_16x16x32_bf16(afr[s], bfr, acc, 0, 0, 0);
        }
#pragma unroll
        for (int r = 0; r < 4; ++r) {
            int m = mbase + quad * 4 + r;   // C/D: row = quad*4+reg, col = l16
            if (m < N_NODES)
                seq_fts[(size_t)m * OUT_FT + tt * 16 + l16] = f2bf_bits(acc[r]);
        }
    }
}

// ================= CSR build via 2-pass radix partition =================
// bucket = dst >> 8 (256 nodes/bucket, 196 buckets). P=256 partition blocks,
// each owning a contiguous chunk of 3125 edges.
#define P 256
#define CHUNK (N_EDGES / P)              // 3125
#define NBUCK ((N_NODES + 255) / 256)    // 196
#define SCAN_B 256
#define NSCAN (NBUCK * P)                // 50176 counts
#define SNBLK (NSCAN / SCAN_B)           // 196 scan blocks (== buckets!)

// pass 1: per-(block,chunk) histogram over buckets, bucket-major layout so the
// scan's per-block partial j == bucket j's total.
__global__ __launch_bounds__(256) void k_phist(const int* __restrict__ dst,
                                               int* __restrict__ cnt) {
    __shared__ int h[NBUCK];
    const int t = threadIdx.x;
    if (t < NBUCK) h[t] = 0;
    __syncthreads();
    const int base = blockIdx.x * CHUNK;
    for (int i = t; i < CHUNK; i += 256)
        atomicAdd(&h[dst[base + i] >> 8], 1);
    __syncthreads();
    if (t < NBUCK) cnt[t * P + blockIdx.x] = h[t];
}

// scan stage A: per-scan-block sums (block j covers cnt[j*256..j*256+256) ==
// bucket j) -> part[j] = bucket j total
__global__ __launch_bounds__(SCAN_B) void k_psum(const int* __restrict__ cnt,
                                                 int* __restrict__ part) {
    int i = blockIdx.x * SCAN_B + threadIdx.x;
    int v = cnt[i];
#pragma unroll
    for (int s = 32; s > 0; s >>= 1) v += __shfl_down(v, s, 64);
    __shared__ int w[4];
    if ((threadIdx.x & 63) == 0) w[threadIdx.x >> 6] = v;
    __syncthreads();
    if (threadIdx.x == 0) part[blockIdx.x] = w[0] + w[1] + w[2] + w[3];
}

// scan stage B: exclusive scan of the 196 bucket totals -> partoff[0..196]
__global__ __launch_bounds__(SCAN_B) void k_scanp(const int* __restrict__ part,
                                                  int* __restrict__ partoff) {
    __shared__ int lds[SCAN_B];
    int tid = threadIdx.x;
    int v = (tid < SNBLK) ? part[tid] : 0;
    lds[tid] = v;
    __syncthreads();
#pragma unroll
    for (int s = 1; s < SCAN_B; s <<= 1) {
        int t2 = (tid >= s) ? lds[tid - s] : 0;
        __syncthreads();
        lds[tid] += t2;
        __syncthreads();
    }
    if (tid < SNBLK) partoff[tid] = lds[tid] - v;   // exclusive
    if (tid == SCAN_B - 1) partoff[SNBLK] = lds[SCAN_B - 1];  // total = N_EDGES
}

// scan stage C: full exclusive scan -> cnt_off[bucket*P + blk]
__global__ __launch_bounds__(SCAN_B) void k_wrscan(const int* __restrict__ cnt,
                                                   const int* __restrict__ partoff,
                                                   int* __restrict__ cnt_off) {
    __shared__ int lds[SCAN_B];
    int tid = threadIdx.x;
    int i = blockIdx.x * SCAN_B + tid;
    int v = cnt[i];
    lds[tid] = v;
    __syncthreads();
#pragma unroll
    for (int s = 1; s < SCAN_B; s <<= 1) {
        int t2 = (tid >= s) ? lds[tid - s] : 0;
        __syncthreads();
        lds[tid] += t2;
        __syncthreads();
    }
    cnt_off[i] = partoff[blockIdx.x] + lds[tid] - v;
}

// pass 2: scatter edges to bucket-grouped part_ev via LDS cursors. Each
// (block,bucket) run is contiguous (~16 recs = 128 B) -> near-zero write amp.
// record: x = final csr payload (src u16 | bf16(val) << 16), y = dst.
__global__ __launch_bounds__(256) void k_pscat(const int* __restrict__ src,
                                               const int* __restrict__ dst,
                                               const float* __restrict__ val,
                                               const int* __restrict__ cnt_off,
                                               uint2* __restrict__ part_ev) {
    __shared__ int off[NBUCK];
    const int t = threadIdx.x;
    if (t < NBUCK) off[t] = cnt_off[t * P + blockIdx.x];
    __syncthreads();
    const int base = blockIdx.x * CHUNK;
    for (int i = t; i < CHUNK; i += 256) {
        int e = base + i;
        int d = dst[e];
        int pos = atomicAdd(&off[d >> 8], 1);
        unsigned x = (unsigned)(unsigned short)src[e]
                   | ((unsigned)f2bf_bits(val[e]) << 16);
        part_ev[pos] = make_uint2(x, (unsigned)d);
    }
}

// final: one block per bucket. Count per-node, local scan -> row_ptr, then
// scatter payloads node-grouped into the block's own contiguous csr region.
// Replaces the old zero/hist/node-scan/fill chain entirely.
__global__ __launch_bounds__(256) void k_fill2(const uint2* __restrict__ part_ev,
                                               const int* __restrict__ partoff,
                                               int* __restrict__ row_ptr,
                                               unsigned* __restrict__ csr_ev) {
    __shared__ int cnt[256];
    __shared__ int lds[256];
    __shared__ int cur[256];
    const int b = blockIdx.x, t = threadIdx.x;
    const int start = partoff[b];
    const int end   = partoff[b + 1];
    cnt[t] = 0;
    __syncthreads();
    for (int i = start + t; i < end; i += 256)
        atomicAdd(&cnt[part_ev[i].y & 255u], 1);
    __syncthreads();
    int v = cnt[t];
    lds[t] = v;
    __syncthreads();
#pragma unroll
    for (int s = 1; s < 256; s <<= 1) {
        int t2 = (t >= s) ? lds[t - s] : 0;
        __syncthreads();
        lds[t] += t2;
        __syncthreads();
    }
    int base = start + lds[t] - v;   // node-exclusive offset
    int n = b * 256 + t;
    if (n <= N_NODES) row_ptr[n] = base;   // n==N_NODES lands in bucket 195: end of node 49999
    cur[t] = base;
    __syncthreads();
    for (int i = start + t; i < end; i += 256) {
        uint2 r = part_ev[i];
        int pos = atomicAdd(&cur[r.y & 255u], 1);
        csr_ev[pos] = r.x;
    }
}

// ---------------- gather + bias + PReLU ----------------
// one wave per node; lane handles features {2*lane, 2*lane+1} -> one dword
// (bf16x2) gathered per edge per lane = 256 B/row, fully coalesced.
#define GW 4
__global__ __launch_bounds__(64 * GW) void k_gather(const unsigned* __restrict__ fts,
                                                    const int* __restrict__ row_ptr,
                                                    const unsigned* __restrict__ csr_ev,
                                                    const float* __restrict__ bias,
                                                    const float* __restrict__ prelu_a,
                                                    float* __restrict__ out) {
    const int wave = threadIdx.x >> 6;
    const int lane = threadIdx.x & 63;
    const int n = blockIdx.x * GW + wave;
    if (n >= N_NODES) return;
    const int s0 = row_ptr[n];
    const int s1 = row_ptr[n + 1];
    float acc0 = 0.f, acc1 = 0.f;
    int j = s0;
    for (; j + 3 < s1; j += 4) {
        unsigned w0 = csr_ev[j],     w1 = csr_ev[j + 1];
        unsigned w2 = csr_ev[j + 2], w3 = csr_ev[j + 3];
        unsigned p0 = fts[(w0 & 0xFFFFu) * 64u + lane];
        unsigned p1 = fts[(w1 & 0xFFFFu) * 64u + lane];
        unsigned p2 = fts[(w2 & 0xFFFFu) * 64u + lane];
        unsigned p3 = fts[(w3 & 0xFFFFu) * 64u + lane];
        float v0 = __uint_as_float(w0 & 0xFFFF0000u);
        float v1 = __uint_as_float(w1 & 0xFFFF0000u);
        float v2 = __uint_as_float(w2 & 0xFFFF0000u);
        float v3 = __uint_as_float(w3 & 0xFFFF0000u);
        acc0 += v0 * __uint_as_float(p0 << 16);
        acc1 += v0 * __uint_as_float(p0 & 0xFFFF0000u);
        acc0 += v1 * __uint_as_float(p1 << 16);
        acc1 += v1 * __uint_as_float(p1 & 0xFFFF0000u);
        acc0 += v2 * __uint_as_float(p2 << 16);
        acc1 += v2 * __uint_as_float(p2 & 0xFFFF0000u);
        acc0 += v3 * __uint_as_float(p3 << 16);
        acc1 += v3 * __uint_as_float(p3 & 0xFFFF0000u);
    }
    for (; j < s1; ++j) {
        unsigned w0 = csr_ev[j];
        unsigned p0 = fts[(w0 & 0xFFFFu) * 64u + lane];
        float v0 = __uint_as_float(w0 & 0xFFFF0000u);
        acc0 += v0 * __uint_as_float(p0 << 16);
        acc1 += v0 * __uint_as_float(p0 & 0xFFFF0000u);
    }
    float2 b = *(const float2*)&bias[lane * 2];
    float a = prelu_a[0];
    float x0 = acc0 + b.x;
    float x1 = acc1 + b.y;
    x0 = (x0 >= 0.f) ? x0 : a * x0;
    x1 = (x1 >= 0.f) ? x1 : a * x1;
    *(float2*)&out[(size_t)n * OUT_FT + lane * 2] = make_float2(x0, x1);
}

extern "C" void kernel_launch(void* const* d_in, const int* in_sizes, int n_in,
                              void* d_out, int out_size, void* d_ws, size_t ws_size,
                              hipStream_t stream) {
    const float* seq      = (const float*)d_in[0];
    const int*   edge_src = (const int*)d_in[1];
    const int*   edge_dst = (const int*)d_in[2];
    const float* edge_val = (const float*)d_in[3];
    const float* W        = (const float*)d_in[4];
    const float* bias     = (const float*)d_in[5];
    const float* prelu_a  = (const float*)d_in[6];
    float* out = (float*)d_out;

    char* ws = (char*)d_ws;
    size_t off = 0;
    auto alloc = [&](size_t bytes) {
        void* p = ws + off;
        off = (off + bytes + 255) & ~(size_t)255;
        return p;
    };
    unsigned short* seq_fts = (unsigned short*)alloc((size_t)N_NODES * OUT_FT * sizeof(unsigned short));
    int*   row_ptr = (int*)alloc((size_t)(N_NODES + 1) * sizeof(int));
    int*   cnt     = (int*)alloc((size_t)NSCAN * sizeof(int));
    int*   cnt_off = (int*)alloc((size_t)NSCAN * sizeof(int));
    int*   part    = (int*)alloc((size_t)SNBLK * sizeof(int));
    int*   partoff = (int*)alloc((size_t)(NBUCK + 1) * sizeof(int));
    uint2* part_ev = (uint2*)alloc((size_t)N_EDGES * sizeof(uint2));
    unsigned* csr_ev = (unsigned*)alloc((size_t)N_EDGES * sizeof(unsigned));
    (void)ws_size; (void)in_sizes; (void)n_in; (void)out_size;

    k_gemm<<<(N_NODES + 63) / 64, 256, 0, stream>>>(seq, W, seq_fts);
    k_phist<<<P, 256, 0, stream>>>(edge_dst, cnt);
    k_psum<<<SNBLK, SCAN_B, 0, stream>>>(cnt, part);
    k_scanp<<<1, SCAN_B, 0, stream>>>(part, partoff);
    k_wrscan<<<SNBLK, SCAN_B, 0, stream>>>(cnt, partoff, cnt_off);
    k_pscat<<<P, 256, 0, stream>>>(edge_src, edge_dst, edge_val, cnt_off, part_ev);
    k_fill2<<<NBUCK, 256, 0, stream>>>(part_ev, partoff, row_ptr, csr_ev);
    k_gather<<<(N_NODES + GW - 1) / GW, 64 * GW, 0, stream>>>((const unsigned*)seq_fts,
                                                              row_ptr, csr_ev,
                                                              bias, prelu_a, out);
}

// Round 7
// 187.197 us; speedup vs baseline: 1.7529x; 1.0598x over previous
//
#include <hip/hip_runtime.h>
#include <hip/hip_bf16.h>

#define N_NODES 50000
#define N_EDGES 800000
#define IN_FT 256
#define OUT_FT 128

typedef __bf16 bf16;
typedef __attribute__((ext_vector_type(8))) __bf16 bf16x8;
typedef __attribute__((ext_vector_type(4))) float floatx4;

static __device__ inline unsigned short f2bf_bits(float f) {
    unsigned u = __float_as_uint(f);
    return (unsigned short)((u + 0x7FFFu + ((u >> 16) & 1u)) >> 16);  // RTNE
}

// ---------------- W pre-convert: fp32 -> bf16, once ----------------
__global__ __launch_bounds__(256) void k_wconv(const float* __restrict__ W,
                                               unsigned short* __restrict__ Wb) {
    int i = blockIdx.x * 256 + threadIdx.x;      // group of 4 floats
    float4 v = ((const float4*)W)[i];
    ushort4 o;
    o.x = f2bf_bits(v.x); o.y = f2bf_bits(v.y);
    o.z = f2bf_bits(v.z); o.w = f2bf_bits(v.w);
    ((ushort4*)Wb)[i] = o;
}

// ---------------- GEMM: seq_fts[n][o] = sum_i seq[n][i] * W[o][i] ----------
// bf16 MFMA (16x16x32). 512 thr = 8 waves, 128 rows/block (wave w: rows
// w*16..w*16+16), all 128 N-cols. Pre-converted bf16 W staged to LDS by plain
// 16B copies. WP=264 padding keeps ds_read_b128 conflict-free.
#define WP 264
#define GM 128

__global__ __launch_bounds__(512) void k_gemm(const float* __restrict__ seq,
                                              const unsigned short* __restrict__ Wb,
                                              unsigned short* __restrict__ seq_fts) {
    __shared__ bf16 Wlds[128 * WP];
    const int t = threadIdx.x;

    // ---- stage Wb -> LDS: thread t copies row t>>2, 64-elem segment (t&3) ----
    {
        const int row = t >> 2, c0 = (t & 3) * 64;
        const unsigned short* src = Wb + row * IN_FT + c0;
        bf16* dst = Wlds + row * WP + c0;
#pragma unroll
        for (int c = 0; c < 8; ++c)
            *(uint4*)(dst + c * 8) = *(const uint4*)(src + c * 8);
    }

    const int lane = t & 63;
    const int wave = t >> 6;
    const int quad = lane >> 4;
    const int l16  = lane & 15;

    // ---- A fragments: lane holds A[m=l16][k=quad*8+j], j=0..7 ----
    int arow = blockIdx.x * GM + wave * 16 + l16;
    if (arow >= N_NODES) arow = 0;            // clamped; stores are guarded
    const float* ap = seq + (size_t)arow * IN_FT + quad * 8;
    bf16x8 afr[8];
#pragma unroll
    for (int s = 0; s < 8; ++s) {
        float4 v0 = *(const float4*)(ap + s * 32);
        float4 v1 = *(const float4*)(ap + s * 32 + 4);
        bf16x8 a;
        a[0] = (bf16)v0.x; a[1] = (bf16)v0.y; a[2] = (bf16)v0.z; a[3] = (bf16)v0.w;
        a[4] = (bf16)v1.x; a[5] = (bf16)v1.y; a[6] = (bf16)v1.z; a[7] = (bf16)v1.w;
        afr[s] = a;
    }
    __syncthreads();

    const int mbase = blockIdx.x * GM + wave * 16;
#pragma unroll
    for (int tt = 0; tt < 8; ++tt) {
        floatx4 acc = {0.f, 0.f, 0.f, 0.f};
        const bf16* bp = Wlds + (tt * 16 + l16) * WP + quad * 8;
#pragma unroll
        for (int s = 0; s < 8; ++s) {
            bf16x8 bfr = *(const bf16x8*)(bp + s * 32);
            acc = __builtin_amdgcn_mfma_f32_16x16x32_bf16(afr[s], bfr, acc, 0, 0, 0);
        }
#pragma unroll
        for (int r = 0; r < 4; ++r) {
            int m = mbase + quad * 4 + r;   // C/D: row = quad*4+reg, col = l16
            if (m < N_NODES)
                seq_fts[(size_t)m * OUT_FT + tt * 16 + l16] = f2bf_bits(acc[r]);
        }
    }
}

// ================= CSR build via 2-pass radix partition =================
// bucket = dst >> 8 (256 nodes/bucket, 196 buckets). P=256 partition blocks,
// each owning a contiguous chunk of 3125 edges.
#define P 256
#define CHUNK (N_EDGES / P)              // 3125
#define NBUCK ((N_NODES + 255) / 256)    // 196
#define SCAN_B 256
#define NSCAN (NBUCK * P)                // 50176 counts
#define SNBLK (NSCAN / SCAN_B)           // 196 scan blocks (== buckets!)

__global__ __launch_bounds__(256) void k_phist(const int* __restrict__ dst,
                                               int* __restrict__ cnt) {
    __shared__ int h[NBUCK];
    const int t = threadIdx.x;
    if (t < NBUCK) h[t] = 0;
    __syncthreads();
    const int base = blockIdx.x * CHUNK;
    for (int i = t; i < CHUNK; i += 256)
        atomicAdd(&h[dst[base + i] >> 8], 1);
    __syncthreads();
    if (t < NBUCK) cnt[t * P + blockIdx.x] = h[t];
}

__global__ __launch_bounds__(SCAN_B) void k_psum(const int* __restrict__ cnt,
                                                 int* __restrict__ part) {
    int i = blockIdx.x * SCAN_B + threadIdx.x;
    int v = cnt[i];
#pragma unroll
    for (int s = 32; s > 0; s >>= 1) v += __shfl_down(v, s, 64);
    __shared__ int w[4];
    if ((threadIdx.x & 63) == 0) w[threadIdx.x >> 6] = v;
    __syncthreads();
    if (threadIdx.x == 0) part[blockIdx.x] = w[0] + w[1] + w[2] + w[3];
}

__global__ __launch_bounds__(SCAN_B) void k_scanp(const int* __restrict__ part,
                                                  int* __restrict__ partoff) {
    __shared__ int lds[SCAN_B];
    int tid = threadIdx.x;
    int v = (tid < SNBLK) ? part[tid] : 0;
    lds[tid] = v;
    __syncthreads();
#pragma unroll
    for (int s = 1; s < SCAN_B; s <<= 1) {
        int t2 = (tid >= s) ? lds[tid - s] : 0;
        __syncthreads();
        lds[tid] += t2;
        __syncthreads();
    }
    if (tid < SNBLK) partoff[tid] = lds[tid] - v;   // exclusive
    if (tid == SCAN_B - 1) partoff[SNBLK] = lds[SCAN_B - 1];  // total = N_EDGES
}

__global__ __launch_bounds__(SCAN_B) void k_wrscan(const int* __restrict__ cnt,
                                                   const int* __restrict__ partoff,
                                                   int* __restrict__ cnt_off) {
    __shared__ int lds[SCAN_B];
    int tid = threadIdx.x;
    int i = blockIdx.x * SCAN_B + tid;
    int v = cnt[i];
    lds[tid] = v;
    __syncthreads();
#pragma unroll
    for (int s = 1; s < SCAN_B; s <<= 1) {
        int t2 = (tid >= s) ? lds[tid - s] : 0;
        __syncthreads();
        lds[tid] += t2;
        __syncthreads();
    }
    cnt_off[i] = partoff[blockIdx.x] + lds[tid] - v;
}

// pass 2: scatter edges to bucket-grouped part_ev via LDS cursors.
// record: x = final csr payload (src u16 | bf16(val) << 16), y = dst.
__global__ __launch_bounds__(256) void k_pscat(const int* __restrict__ src,
                                               const int* __restrict__ dst,
                                               const float* __restrict__ val,
                                               const int* __restrict__ cnt_off,
                                               uint2* __restrict__ part_ev) {
    __shared__ int off[NBUCK];
    const int t = threadIdx.x;
    if (t < NBUCK) off[t] = cnt_off[t * P + blockIdx.x];
    __syncthreads();
    const int base = blockIdx.x * CHUNK;
    for (int i = t; i < CHUNK; i += 256) {
        int e = base + i;
        int d = dst[e];
        int pos = atomicAdd(&off[d >> 8], 1);
        unsigned x = (unsigned)(unsigned short)src[e]
                   | ((unsigned)f2bf_bits(val[e]) << 16);
        part_ev[pos] = make_uint2(x, (unsigned)d);
    }
}

// final: one block per bucket. Count per-node, local scan -> row_ptr, then
// scatter payloads node-grouped into the block's own contiguous csr region.
__global__ __launch_bounds__(256) void k_fill2(const uint2* __restrict__ part_ev,
                                               const int* __restrict__ partoff,
                                               int* __restrict__ row_ptr,
                                               unsigned* __restrict__ csr_ev) {
    __shared__ int cnt[256];
    __shared__ int lds[256];
    __shared__ int cur[256];
    const int b = blockIdx.x, t = threadIdx.x;
    const int start = partoff[b];
    const int end   = partoff[b + 1];
    cnt[t] = 0;
    __syncthreads();
    for (int i = start + t; i < end; i += 256)
        atomicAdd(&cnt[part_ev[i].y & 255u], 1);
    __syncthreads();
    int v = cnt[t];
    lds[t] = v;
    __syncthreads();
#pragma unroll
    for (int s = 1; s < 256; s <<= 1) {
        int t2 = (t >= s) ? lds[t - s] : 0;
        __syncthreads();
        lds[t] += t2;
        __syncthreads();
    }
    int base = start + lds[t] - v;   // node-exclusive offset
    int n = b * 256 + t;
    if (n <= N_NODES) row_ptr[n] = base;
    cur[t] = base;
    __syncthreads();
    for (int i = start + t; i < end; i += 256) {
        uint2 r = part_ev[i];
        int pos = atomicAdd(&cur[r.y & 255u], 1);
        csr_ev[pos] = r.x;
    }
}

// ---------------- gather + bias + PReLU ----------------
#define GW 4
__global__ __launch_bounds__(64 * GW) void k_gather(const unsigned* __restrict__ fts,
                                                    const int* __restrict__ row_ptr,
                                                    const unsigned* __restrict__ csr_ev,
                                                    const float* __restrict__ bias,
                                                    const float* __restrict__ prelu_a,
                                                    float* __restrict__ out) {
    const int wave = threadIdx.x >> 6;
    const int lane = threadIdx.x & 63;
    const int n = blockIdx.x * GW + wave;
    if (n >= N_NODES) return;
    const int s0 = row_ptr[n];
    const int s1 = row_ptr[n + 1];
    float acc0 = 0.f, acc1 = 0.f;
    int j = s0;
    for (; j + 3 < s1; j += 4) {
        unsigned w0 = csr_ev[j],     w1 = csr_ev[j + 1];
        unsigned w2 = csr_ev[j + 2], w3 = csr_ev[j + 3];
        unsigned p0 = fts[(w0 & 0xFFFFu) * 64u + lane];
        unsigned p1 = fts[(w1 & 0xFFFFu) * 64u + lane];
        unsigned p2 = fts[(w2 & 0xFFFFu) * 64u + lane];
        unsigned p3 = fts[(w3 & 0xFFFFu) * 64u + lane];
        float v0 = __uint_as_float(w0 & 0xFFFF0000u);
        float v1 = __uint_as_float(w1 & 0xFFFF0000u);
        float v2 = __uint_as_float(w2 & 0xFFFF0000u);
        float v3 = __uint_as_float(w3 & 0xFFFF0000u);
        acc0 += v0 * __uint_as_float(p0 << 16);
        acc1 += v0 * __uint_as_float(p0 & 0xFFFF0000u);
        acc0 += v1 * __uint_as_float(p1 << 16);
        acc1 += v1 * __uint_as_float(p1 & 0xFFFF0000u);
        acc0 += v2 * __uint_as_float(p2 << 16);
        acc1 += v2 * __uint_as_float(p2 & 0xFFFF0000u);
        acc0 += v3 * __uint_as_float(p3 << 16);
        acc1 += v3 * __uint_as_float(p3 & 0xFFFF0000u);
    }
    for (; j < s1; ++j) {
        unsigned w0 = csr_ev[j];
        unsigned p0 = fts[(w0 & 0xFFFFu) * 64u + lane];
        float v0 = __uint_as_float(w0 & 0xFFFF0000u);
        acc0 += v0 * __uint_as_float(p0 << 16);
        acc1 += v0 * __uint_as_float(p0 & 0xFFFF0000u);
    }
    float2 b = *(const float2*)&bias[lane * 2];
    float a = prelu_a[0];
    float x0 = acc0 + b.x;
    float x1 = acc1 + b.y;
    x0 = (x0 >= 0.f) ? x0 : a * x0;
    x1 = (x1 >= 0.f) ? x1 : a * x1;
    *(float2*)&out[(size_t)n * OUT_FT + lane * 2] = make_float2(x0, x1);
}

extern "C" void kernel_launch(void* const* d_in, const int* in_sizes, int n_in,
                              void* d_out, int out_size, void* d_ws, size_t ws_size,
                              hipStream_t stream) {
    const float* seq      = (const float*)d_in[0];
    const int*   edge_src = (const int*)d_in[1];
    const int*   edge_dst = (const int*)d_in[2];
    const float* edge_val = (const float*)d_in[3];
    const float* W        = (const float*)d_in[4];
    const float* bias     = (const float*)d_in[5];
    const float* prelu_a  = (const float*)d_in[6];
    float* out = (float*)d_out;

    char* ws = (char*)d_ws;
    size_t off = 0;
    auto alloc = [&](size_t bytes) {
        void* p = ws + off;
        off = (off + bytes + 255) & ~(size_t)255;
        return p;
    };
    unsigned short* seq_fts = (unsigned short*)alloc((size_t)N_NODES * OUT_FT * sizeof(unsigned short));
    unsigned short* Wb      = (unsigned short*)alloc((size_t)OUT_FT * IN_FT * sizeof(unsigned short));
    int*   row_ptr = (int*)alloc((size_t)(N_NODES + 1) * sizeof(int));
    int*   cnt     = (int*)alloc((size_t)NSCAN * sizeof(int));
    int*   cnt_off = (int*)alloc((size_t)NSCAN * sizeof(int));
    int*   part    = (int*)alloc((size_t)SNBLK * sizeof(int));
    int*   partoff = (int*)alloc((size_t)(NBUCK + 1) * sizeof(int));
    uint2* part_ev = (uint2*)alloc((size_t)N_EDGES * sizeof(uint2));
    unsigned* csr_ev = (unsigned*)alloc((size_t)N_EDGES * sizeof(unsigned));
    (void)ws_size; (void)in_sizes; (void)n_in; (void)out_size;

    k_wconv<<<(OUT_FT * IN_FT / 4) / 256, 256, 0, stream>>>(W, Wb);
    k_gemm<<<(N_NODES + GM - 1) / GM, 512, 0, stream>>>(seq, Wb, seq_fts);
    k_phist<<<P, 256, 0, stream>>>(edge_dst, cnt);
    k_psum<<<SNBLK, SCAN_B, 0, stream>>>(cnt, part);
    k_scanp<<<1, SCAN_B, 0, stream>>>(part, partoff);
    k_wrscan<<<SNBLK, SCAN_B, 0, stream>>>(cnt, partoff, cnt_off);
    k_pscat<<<P, 256, 0, stream>>>(edge_src, edge_dst, edge_val, cnt_off, part_ev);
    k_fill2<<<NBUCK, 256, 0, stream>>>(part_ev, partoff, row_ptr, csr_ev);
    k_gather<<<(N_NODES + GW - 1) / GW, 64 * GW, 0, stream>>>((const unsigned*)seq_fts,
                                                              row_ptr, csr_ev,
                                                              bias, prelu_a, out);
}

// Round 8
// 181.388 us; speedup vs baseline: 1.8090x; 1.0320x over previous
//
#include <hip/hip_runtime.h>
#include <hip/hip_bf16.h>

#define N_NODES 50000
#define N_EDGES 800000
#define IN_FT 256
#define OUT_FT 128

typedef __bf16 bf16;
typedef __attribute__((ext_vector_type(8))) __bf16 bf16x8;
typedef __attribute__((ext_vector_type(4))) float floatx4;

static __device__ inline unsigned short f2bf_bits(float f) {
    unsigned u = __float_as_uint(f);
    return (unsigned short)((u + 0x7FFFu + ((u >> 16) & 1u)) >> 16);  // RTNE
}

// ================= config =================
#define P 256
#define CHUNK (N_EDGES / P)              // 3125
#define NBUCK ((N_NODES + 255) / 256)    // 196
#define NSCAN (NBUCK * P)                // 50176 counts
#define GM 128
#define GEMM_BLKS ((N_NODES + GM - 1) / GM)   // 391
#define WP 264

// ============ launch 1: phist (blocks 0..255) + status/ticket zero (block 256)
//              + wconv (blocks 257..288), all independent ============
__global__ __launch_bounds__(256) void k_prep(const float* __restrict__ W,
                                              const int* __restrict__ dst,
                                              unsigned short* __restrict__ Wb,
                                              int* __restrict__ cnt,
                                              unsigned long long* __restrict__ status,
                                              int* __restrict__ ticket) {
    const int b = blockIdx.x, t = threadIdx.x;
    if (b < P) {
        // --- per-chunk histogram over buckets (bucket-major output) ---
        __shared__ int h[NBUCK];
        if (t < NBUCK) h[t] = 0;
        __syncthreads();
        const int base = b * CHUNK;
        for (int i = t; i < CHUNK; i += 256)
            atomicAdd(&h[dst[base + i] >> 8], 1);
        __syncthreads();
        if (t < NBUCK) cnt[t * P + b] = h[t];
    } else if (b == P) {
        // --- zero lookback state (ws is poisoned 0xAA every call) ---
        if (t < NBUCK) status[t] = 0ull;
        if (t == 255) *ticket = 0;
    } else {
        // --- W fp32 -> bf16 ---
        int i = (b - P - 1) * 256 + t;          // group of 4 floats, 8192 total
        float4 v = ((const float4*)W)[i];
        ushort4 o;
        o.x = f2bf_bits(v.x); o.y = f2bf_bits(v.y);
        o.z = f2bf_bits(v.z); o.w = f2bf_bits(v.w);
        ((ushort4*)Wb)[i] = o;
    }
}

// ============ launch 2: gemm (blocks 0..390) ∪ lookback scan (blocks 391..586)
// The two halves are independent (gemm needs Wb; scan needs cnt) and overlap
// inside one dispatch. ============
__global__ __launch_bounds__(512) void k_gemm_scan(const float* __restrict__ seq,
                                                   const unsigned short* __restrict__ Wb,
                                                   unsigned short* __restrict__ seq_fts,
                                                   const int* __restrict__ cnt,
                                                   int* __restrict__ cnt_off,
                                                   int* __restrict__ partoff,
                                                   unsigned long long* __restrict__ status,
                                                   int* __restrict__ ticket) {
    const int t = threadIdx.x;
    if (blockIdx.x < GEMM_BLKS) {
        // ---------------- bf16 MFMA GEMM, 128 rows/block ----------------
        __shared__ bf16 Wlds[128 * WP];
        {
            const int row = t >> 2, c0 = (t & 3) * 64;
            const unsigned short* src = Wb + row * IN_FT + c0;
            bf16* dstp = Wlds + row * WP + c0;
#pragma unroll
            for (int c = 0; c < 8; ++c)
                *(uint4*)(dstp + c * 8) = *(const uint4*)(src + c * 8);
        }
        const int lane = t & 63;
        const int wave = t >> 6;
        const int quad = lane >> 4;
        const int l16  = lane & 15;

        int arow = blockIdx.x * GM + wave * 16 + l16;
        if (arow >= N_NODES) arow = 0;            // clamped; stores guarded
        const float* ap = seq + (size_t)arow * IN_FT + quad * 8;
        bf16x8 afr[8];
#pragma unroll
        for (int s = 0; s < 8; ++s) {
            float4 v0 = *(const float4*)(ap + s * 32);
            float4 v1 = *(const float4*)(ap + s * 32 + 4);
            bf16x8 a;
            a[0] = (bf16)v0.x; a[1] = (bf16)v0.y; a[2] = (bf16)v0.z; a[3] = (bf16)v0.w;
            a[4] = (bf16)v1.x; a[5] = (bf16)v1.y; a[6] = (bf16)v1.z; a[7] = (bf16)v1.w;
            afr[s] = a;
        }
        __syncthreads();

        const int mbase = blockIdx.x * GM + wave * 16;
#pragma unroll
        for (int tt = 0; tt < 8; ++tt) {
            floatx4 acc = {0.f, 0.f, 0.f, 0.f};
            const bf16* bp = Wlds + (tt * 16 + l16) * WP + quad * 8;
#pragma unroll
            for (int s = 0; s < 8; ++s) {
                bf16x8 bfr = *(const bf16x8*)(bp + s * 32);
                acc = __builtin_amdgcn_mfma_f32_16x16x32_bf16(afr[s], bfr, acc, 0, 0, 0);
            }
#pragma unroll
            for (int r = 0; r < 4; ++r) {
                int m = mbase + quad * 4 + r;   // C/D: row = quad*4+reg, col = l16
                if (m < N_NODES)
                    seq_fts[(size_t)m * OUT_FT + tt * 16 + l16] = f2bf_bits(acc[r]);
            }
        }
    } else {
        // ------------- decoupled-lookback scan, tile == bucket -------------
        __shared__ int lds2[256];
        __shared__ int stile;
        __shared__ unsigned run_sh;
        if (t == 0) stile = atomicAdd(ticket, 1);
        __syncthreads();
        const int j = stile;
        int v = (t < 256) ? cnt[j * 256 + t] : 0;
        if (t < 256) lds2[t] = v;
        __syncthreads();
        for (int s = 1; s < 256; s <<= 1) {
            int add = (t < 256 && t >= s) ? lds2[t - s] : 0;
            __syncthreads();
            if (t < 256) lds2[t] += add;
            __syncthreads();
        }
        const unsigned total = (unsigned)lds2[255];
        if (t == 0) {
            if (j == 0) {
                atomicExch(&status[0], ((unsigned long long)total << 2) | 2ull);
                run_sh = 0;
            } else {
                atomicExch(&status[j], ((unsigned long long)total << 2) | 1ull);
                unsigned running = 0;
                int k = j - 1;
                for (;;) {
                    unsigned long long s = atomicAdd(&status[k], 0ull);
                    unsigned st = (unsigned)(s & 3ull);
                    if (st == 0u) { __builtin_amdgcn_s_sleep(1); continue; }
                    running += (unsigned)(s >> 2);
                    if (st == 2u) break;
                    --k;
                }
                atomicExch(&status[j],
                           ((unsigned long long)(running + total) << 2) | 2ull);
                run_sh = running;
            }
        }
        __syncthreads();
        const int base = (int)run_sh;
        if (t < 256) cnt_off[j * 256 + t] = base + lds2[t] - v;
        if (t == 0) partoff[j] = base;
        if (t == 0 && j == NBUCK - 1) partoff[NBUCK] = base + (int)total;
    }
}

// ============ launch 3: partition scatter ============
// record: x = final csr payload (src u16 | bf16(val) << 16), y = dst.
__global__ __launch_bounds__(256) void k_pscat(const int* __restrict__ src,
                                               const int* __restrict__ dst,
                                               const float* __restrict__ val,
                                               const int* __restrict__ cnt_off,
                                               uint2* __restrict__ part_ev) {
    __shared__ int off[NBUCK];
    const int t = threadIdx.x;
    if (t < NBUCK) off[t] = cnt_off[t * P + blockIdx.x];
    __syncthreads();
    const int base = blockIdx.x * CHUNK;
    for (int i = t; i < CHUNK; i += 256) {
        int e = base + i;
        int d = dst[e];
        int pos = atomicAdd(&off[d >> 8], 1);
        unsigned x = (unsigned)(unsigned short)src[e]
                   | ((unsigned)f2bf_bits(val[e]) << 16);
        part_ev[pos] = make_uint2(x, (unsigned)d);
    }
}

// ============ launch 4: per-bucket node grouping -> row_ptr + csr_ev ============
__global__ __launch_bounds__(256) void k_fill2(const uint2* __restrict__ part_ev,
                                               const int* __restrict__ partoff,
                                               int* __restrict__ row_ptr,
                                               unsigned* __restrict__ csr_ev) {
    __shared__ int cnt[256];
    __shared__ int lds[256];
    __shared__ int cur[256];
    const int b = blockIdx.x, t = threadIdx.x;
    const int start = partoff[b];
    const int end   = partoff[b + 1];
    cnt[t] = 0;
    __syncthreads();
    for (int i = start + t; i < end; i += 256)
        atomicAdd(&cnt[part_ev[i].y & 255u], 1);
    __syncthreads();
    int v = cnt[t];
    lds[t] = v;
    __syncthreads();
#pragma unroll
    for (int s = 1; s < 256; s <<= 1) {
        int t2 = (t >= s) ? lds[t - s] : 0;
        __syncthreads();
        lds[t] += t2;
        __syncthreads();
    }
    int base = start + lds[t] - v;   // node-exclusive offset
    int n = b * 256 + t;
    if (n <= N_NODES) row_ptr[n] = base;
    cur[t] = base;
    __syncthreads();
    for (int i = start + t; i < end; i += 256) {
        uint2 r = part_ev[i];
        int pos = atomicAdd(&cur[r.y & 255u], 1);
        csr_ev[pos] = r.x;
    }
}

// ============ launch 5: gather + bias + PReLU ============
#define GW 4
__global__ __launch_bounds__(64 * GW) void k_gather(const unsigned* __restrict__ fts,
                                                    const int* __restrict__ row_ptr,
                                                    const unsigned* __restrict__ csr_ev,
                                                    const float* __restrict__ bias,
                                                    const float* __restrict__ prelu_a,
                                                    float* __restrict__ out) {
    const int wave = threadIdx.x >> 6;
    const int lane = threadIdx.x & 63;
    const int n = blockIdx.x * GW + wave;
    if (n >= N_NODES) return;
    const int s0 = row_ptr[n];
    const int s1 = row_ptr[n + 1];
    float acc0 = 0.f, acc1 = 0.f;
    int j = s0;
    for (; j + 3 < s1; j += 4) {
        unsigned w0 = csr_ev[j],     w1 = csr_ev[j + 1];
        unsigned w2 = csr_ev[j + 2], w3 = csr_ev[j + 3];
        unsigned p0 = fts[(w0 & 0xFFFFu) * 64u + lane];
        unsigned p1 = fts[(w1 & 0xFFFFu) * 64u + lane];
        unsigned p2 = fts[(w2 & 0xFFFFu) * 64u + lane];
        unsigned p3 = fts[(w3 & 0xFFFFu) * 64u + lane];
        float v0 = __uint_as_float(w0 & 0xFFFF0000u);
        float v1 = __uint_as_float(w1 & 0xFFFF0000u);
        float v2 = __uint_as_float(w2 & 0xFFFF0000u);
        float v3 = __uint_as_float(w3 & 0xFFFF0000u);
        acc0 += v0 * __uint_as_float(p0 << 16);
        acc1 += v0 * __uint_as_float(p0 & 0xFFFF0000u);
        acc0 += v1 * __uint_as_float(p1 << 16);
        acc1 += v1 * __uint_as_float(p1 & 0xFFFF0000u);
        acc0 += v2 * __uint_as_float(p2 << 16);
        acc1 += v2 * __uint_as_float(p2 & 0xFFFF0000u);
        acc0 += v3 * __uint_as_float(p3 << 16);
        acc1 += v3 * __uint_as_float(p3 & 0xFFFF0000u);
    }
    for (; j < s1; ++j) {
        unsigned w0 = csr_ev[j];
        unsigned p0 = fts[(w0 & 0xFFFFu) * 64u + lane];
        float v0 = __uint_as_float(w0 & 0xFFFF0000u);
        acc0 += v0 * __uint_as_float(p0 << 16);
        acc1 += v0 * __uint_as_float(p0 & 0xFFFF0000u);
    }
    float2 b = *(const float2*)&bias[lane * 2];
    float a = prelu_a[0];
    float x0 = acc0 + b.x;
    float x1 = acc1 + b.y;
    x0 = (x0 >= 0.f) ? x0 : a * x0;
    x1 = (x1 >= 0.f) ? x1 : a * x1;
    *(float2*)&out[(size_t)n * OUT_FT + lane * 2] = make_float2(x0, x1);
}

extern "C" void kernel_launch(void* const* d_in, const int* in_sizes, int n_in,
                              void* d_out, int out_size, void* d_ws, size_t ws_size,
                              hipStream_t stream) {
    const float* seq      = (const float*)d_in[0];
    const int*   edge_src = (const int*)d_in[1];
    const int*   edge_dst = (const int*)d_in[2];
    const float* edge_val = (const float*)d_in[3];
    const float* W        = (const float*)d_in[4];
    const float* bias     = (const float*)d_in[5];
    const float* prelu_a  = (const float*)d_in[6];
    float* out = (float*)d_out;

    char* ws = (char*)d_ws;
    size_t off = 0;
    auto alloc = [&](size_t bytes) {
        void* p = ws + off;
        off = (off + bytes + 255) & ~(size_t)255;
        return p;
    };
    unsigned short* seq_fts = (unsigned short*)alloc((size_t)N_NODES * OUT_FT * sizeof(unsigned short));
    unsigned short* Wb      = (unsigned short*)alloc((size_t)OUT_FT * IN_FT * sizeof(unsigned short));
    int*   row_ptr = (int*)alloc((size_t)(N_NODES + 1) * sizeof(int));
    int*   cnt     = (int*)alloc((size_t)NSCAN * sizeof(int));
    int*   cnt_off = (int*)alloc((size_t)NSCAN * sizeof(int));
    int*   partoff = (int*)alloc((size_t)(NBUCK + 1) * sizeof(int));
    unsigned long long* status = (unsigned long long*)alloc((size_t)NBUCK * sizeof(unsigned long long));
    int*   ticket  = (int*)alloc(256);
    uint2* part_ev = (uint2*)alloc((size_t)N_EDGES * sizeof(uint2));
    unsigned* csr_ev = (unsigned*)alloc((size_t)N_EDGES * sizeof(unsigned));
    (void)ws_size; (void)in_sizes; (void)n_in; (void)out_size;

    k_prep<<<P + 1 + 32, 256, 0, stream>>>(W, edge_dst, Wb, cnt, status, ticket);
    k_gemm_scan<<<GEMM_BLKS + NBUCK, 512, 0, stream>>>(seq, Wb, seq_fts, cnt,
                                                       cnt_off, partoff, status, ticket);
    k_pscat<<<P, 256, 0, stream>>>(edge_src, edge_dst, edge_val, cnt_off, part_ev);
    k_fill2<<<NBUCK, 256, 0, stream>>>(part_ev, partoff, row_ptr, csr_ev);
    k_gather<<<(N_NODES + GW - 1) / GW, 64 * GW, 0, stream>>>((const unsigned*)seq_fts,
                                                              row_ptr, csr_ev,
                                                              bias, prelu_a, out);
}